// Round 3
// baseline (972.814 us; speedup 1.0000x reference)
//
#include <hip/hip_runtime.h>
#include <hip/hip_bf16.h>

// Problem constants
#define TQn 1024
#define Bn  16
#define Hn  1024
#define Sn  4096

#define BM 128   // s-tile
#define BN 128   // t-tile
#define BK 64
#define NKS (Hn / BK)   // 16 k-steps

typedef _Float16 f16x8 __attribute__((ext_vector_type(8)));
typedef float    f32x4 __attribute__((ext_vector_type(4)));

__device__ __forceinline__ void cvt_split(const f32x4& v0, const f32x4& v1,
                                          f16x8& hi, f16x8& lo) {
#pragma unroll
  for (int e = 0; e < 4; ++e) {
    _Float16 h = (_Float16)v0[e];
    hi[e] = h;
    lo[e] = (_Float16)(v0[e] - (float)h);
  }
#pragma unroll
  for (int e = 0; e < 4; ++e) {
    _Float16 h = (_Float16)v1[e];
    hi[4 + e] = h;
    lo[4 + e] = (_Float16)(v1[e] - (float)h);
  }
}

// scores[b,s,t] = sum_h enc[s,b,h]*hid[t,b,h];  P = exp(tanh(scores))
// out <- P ; sums[b,t] <- sum_s P (atomic)
__global__ __launch_bounds__(256, 2)
void att_gemm(const float* __restrict__ hid,   // [TQ,B,H]
              const float* __restrict__ enc,   // [S,B,H]
              float* __restrict__ out,         // [B,S,TQ]
              float* __restrict__ sums)        // [B,TQ]
{
  // LDS planes as 16B units: 128 rows x 8 units each -> 16KB per plane, 64KB total
  __shared__ f16x8 sAhi[BM * BK / 8];
  __shared__ f16x8 sAlo[BM * BK / 8];
  __shared__ f16x8 sBhi[BN * BK / 8];
  __shared__ f16x8 sBlo[BN * BK / 8];

  const int tid  = threadIdx.x;
  const int lane = tid & 63;
  const int wv   = tid >> 6;
  const int wm   = (wv >> 1) << 6;   // wave row offset (0/64)
  const int wn   = (wv & 1) << 6;    // wave col offset (0/64)

  const int b  = blockIdx.z;
  const int s0 = blockIdx.y * BM;
  const int t0 = blockIdx.x * BN;

  // staging decomposition: 8-elem (16B-f16 after cvt) units; 8 units/row
  const int unit = tid & 7;
  const int row0 = tid >> 3;         // rows row0 + 32*i, i=0..3

  const float* encB = enc + (size_t)b * Hn;
  const float* hidB = hid + (size_t)b * Hn;
  const size_t ldg = (size_t)Bn * Hn;   // 16384 floats between rows

  f32x4 acc[4][4];
#pragma unroll
  for (int m = 0; m < 4; ++m)
#pragma unroll
    for (int n = 0; n < 4; ++n)
      acc[m][n] = (f32x4){0.f, 0.f, 0.f, 0.f};

  f32x4 ra[4][2], rb[4][2];

  // ---- prologue: load tile 0 ----
#pragma unroll
  for (int i = 0; i < 4; ++i) {
    const float* pa = encB + (size_t)(s0 + row0 + 32 * i) * ldg + unit * 8;
    ra[i][0] = *(const f32x4*)pa;
    ra[i][1] = *(const f32x4*)(pa + 4);
    const float* pb = hidB + (size_t)(t0 + row0 + 32 * i) * ldg + unit * 8;
    rb[i][0] = *(const f32x4*)pb;
    rb[i][1] = *(const f32x4*)(pb + 4);
  }
  // convert + swizzled LDS write (tile 0)
#pragma unroll
  for (int i = 0; i < 4; ++i) {
    const int row = row0 + 32 * i;
    const int u   = unit ^ (row & 7);
    f16x8 hi, lo;
    cvt_split(ra[i][0], ra[i][1], hi, lo);
    sAhi[row * 8 + u] = hi;
    sAlo[row * 8 + u] = lo;
    cvt_split(rb[i][0], rb[i][1], hi, lo);
    sBhi[row * 8 + u] = hi;
    sBlo[row * 8 + u] = lo;
  }
  __syncthreads();

#pragma unroll 1
  for (int ks = 0; ks < NKS; ++ks) {
    // issue global loads for next k-tile (hide latency under MFMA)
    if (ks + 1 < NKS) {
      const int ko = (ks + 1) * BK;
#pragma unroll
      for (int i = 0; i < 4; ++i) {
        const float* pa = encB + (size_t)(s0 + row0 + 32 * i) * ldg + ko + unit * 8;
        ra[i][0] = *(const f32x4*)pa;
        ra[i][1] = *(const f32x4*)(pa + 4);
        const float* pb = hidB + (size_t)(t0 + row0 + 32 * i) * ldg + ko + unit * 8;
        rb[i][0] = *(const f32x4*)pb;
        rb[i][1] = *(const f32x4*)(pb + 4);
      }
    }

    // compute current LDS tile: 2 K=32 slices
#pragma unroll
    for (int sl = 0; sl < 2; ++sl) {
      const int ko = sl * 4 + (lane >> 4);   // 16B unit along k
      f16x8 ah[4], al[4], bh[4], bl[4];
#pragma unroll
      for (int m = 0; m < 4; ++m) {
        const int r = wm + m * 16 + (lane & 15);
        const int u = ko ^ (r & 7);
        ah[m] = sAhi[r * 8 + u];
        al[m] = sAlo[r * 8 + u];
      }
#pragma unroll
      for (int n = 0; n < 4; ++n) {
        const int r = wn + n * 16 + (lane & 15);
        const int u = ko ^ (r & 7);
        bh[n] = sBhi[r * 8 + u];
        bl[n] = sBlo[r * 8 + u];
      }
#pragma unroll
      for (int m = 0; m < 4; ++m)
#pragma unroll
        for (int n = 0; n < 4; ++n) {
          acc[m][n] = __builtin_amdgcn_mfma_f32_16x16x32_f16(ah[m], bh[n], acc[m][n], 0, 0, 0);
          acc[m][n] = __builtin_amdgcn_mfma_f32_16x16x32_f16(ah[m], bl[n], acc[m][n], 0, 0, 0);
          acc[m][n] = __builtin_amdgcn_mfma_f32_16x16x32_f16(al[m], bh[n], acc[m][n], 0, 0, 0);
        }
    }
    __syncthreads();

    if (ks + 1 < NKS) {
#pragma unroll
      for (int i = 0; i < 4; ++i) {
        const int row = row0 + 32 * i;
        const int u   = unit ^ (row & 7);
        f16x8 hi, lo;
        cvt_split(ra[i][0], ra[i][1], hi, lo);
        sAhi[row * 8 + u] = hi;
        sAlo[row * 8 + u] = lo;
        cvt_split(rb[i][0], rb[i][1], hi, lo);
        sBhi[row * 8 + u] = hi;
        sBlo[row * 8 + u] = lo;
      }
    }
    __syncthreads();
  }

  // ---- epilogue: P = exp(tanh(score)), store + column sums ----
  // C/D layout: col = lane&15, row = (lane>>4)*4 + j   [measured m89/m91]
#pragma unroll
  for (int n = 0; n < 4; ++n) {
    const int t = t0 + wn + n * 16 + (lane & 15);
    float csum = 0.f;
#pragma unroll
    for (int m = 0; m < 4; ++m) {
      const int sb = s0 + wm + m * 16 + ((lane >> 4) << 2);
#pragma unroll
      for (int j = 0; j < 4; ++j) {
        const float x  = acc[m][n][j];
        const float w  = __expf(tanhf(x));
        out[((size_t)b * Sn + (sb + j)) * TQn + t] = w;
        csum += w;
      }
    }
    csum += __shfl_xor(csum, 16, 64);
    csum += __shfl_xor(csum, 32, 64);
    if ((lane >> 4) == 0)
      atomicAdd(&sums[b * TQn + t], csum);
  }
}

__global__ void zero_kernel(float* __restrict__ p, int n) {
  int i = blockIdx.x * 256 + threadIdx.x;
  if (i < n) p[i] = 0.f;
}

// in-place: sums <- 1/sums
__global__ void inv_kernel(float* __restrict__ sums, int n) {
  int i = blockIdx.x * 256 + threadIdx.x;
  if (i < n) sums[i] = 1.0f / sums[i];
}

__global__ __launch_bounds__(256)
void scale_kernel(float* __restrict__ out, const float* __restrict__ inv) {
  const int total4 = Bn * Sn * TQn / 4;         // 16,777,216
  f32x4* o4 = (f32x4*)out;
  const f32x4* i4 = (const f32x4*)inv;
  const int stride = gridDim.x * blockDim.x;
  for (int i = blockIdx.x * blockDim.x + threadIdx.x; i < total4; i += stride) {
    const int tq = i & 255;          // TQ/4 = 256
    const int bb = i >> 20;          // / (S*TQ/4) = 2^20
    f32x4 v = o4[i];
    f32x4 s = i4[bb * 256 + tq];
    o4[i] = v * s;
  }
}

extern "C" void kernel_launch(void* const* d_in, const int* in_sizes, int n_in,
                              void* d_out, int out_size, void* d_ws, size_t ws_size,
                              hipStream_t stream) {
  const float* hid = (const float*)d_in[0];   // hiddenState [TQ,B,H]
  const float* enc = (const float*)d_in[1];   // encoderOut  [S,B,H]
  float* out  = (float*)d_out;                // [B,S,TQ]
  float* sums = (float*)d_ws;                 // [B*TQ] floats (64 KB)

  const int nsum = Bn * TQn;                  // 16384
  zero_kernel<<<(nsum + 255) / 256, 256, 0, stream>>>(sums, nsum);

  dim3 grid(TQn / BN, Sn / BM, Bn);           // (8, 32, 16)
  att_gemm<<<grid, 256, 0, stream>>>(hid, enc, out, sums);

  inv_kernel<<<(nsum + 255) / 256, 256, 0, stream>>>(sums, nsum);

  scale_kernel<<<2048, 256, 0, stream>>>(out, sums);
}